// Round 19
// baseline (251.919 us; speedup 1.0000x reference)
//
#include <hip/hip_runtime.h>
#include <hip/hip_bf16.h>
#include <math.h>

#define S_LEN 4096
#define DMODEL 1024
#define NHEADS 16
#define DHEAD 64

typedef unsigned short u16;
typedef short bf16x8 __attribute__((ext_vector_type(8)));
typedef float f32x4 __attribute__((ext_vector_type(4)));
typedef u16 u16x4 __attribute__((ext_vector_type(4)));
typedef u16 u16x8 __attribute__((ext_vector_type(8)));
typedef unsigned uint4v __attribute__((ext_vector_type(4)));
typedef unsigned uint2v __attribute__((ext_vector_type(2)));

__device__ __forceinline__ u16 f2bf(float f) {
    unsigned u = __builtin_bit_cast(unsigned, f);
    u = (u + 0x7FFFu + ((u >> 16) & 1u)) >> 16;
    return (u16)u;
}
__device__ __forceinline__ float bf2f(u16 b) {
    return __builtin_bit_cast(float, ((unsigned)b) << 16);
}
// packed f32x2 -> u32 of 2 bf16 (RNE) via HIP intrinsic type; memcpy = free bitcast in IR
__device__ __forceinline__ unsigned pack2bf(float lo, float hi) {
    __hip_bfloat162 c = __float22bfloat162_rn(make_float2(lo, hi));
    unsigned u;
    __builtin_memcpy(&u, &c, 4);
    return u;
}

// async global->LDS, 16B per lane; LDS dest = wave-uniform base + lane*16
__device__ __forceinline__ void gload16(const void* g, void* l) {
    __builtin_amdgcn_global_load_lds((const __attribute__((address_space(1))) void*)g,
                                     (__attribute__((address_space(3))) void*)l, 16, 0, 0);
}

// ---------------- RoPE tables (fp32-faithful to numpy float32 path) ----------------
__global__ void rope_table_kernel(float* __restrict__ cost, float* __restrict__ sint) {
    int tid = blockIdx.x * blockDim.x + threadIdx.x;  // 4096*32
    int i = tid & 31;
    int pos = tid >> 5;
    double e = (double)(2 * i) / 64.0;
    float t32 = (float)pow(10000.0, e);
    float freq = 1.0f / t32;
    float ang = (float)pos * freq;
    cost[tid] = (float)cos((double)ang);
    sint[tid] = (float)sin((double)ang);
}

// ---------------- fp32 -> bf16 hi (+ optional lo residual) ----------------
__global__ void split_kernel(const float* __restrict__ in, u16* __restrict__ hi,
                             u16* __restrict__ lo, int n4) {
    int i = blockIdx.x * blockDim.x + threadIdx.x;
    if (i >= n4) return;
    float4 v = ((const float4*)in)[i];
    float f[4] = {v.x, v.y, v.z, v.w};
    u16x4 h, l;
#pragma unroll
    for (int j = 0; j < 4; j++) {
        h[j] = f2bf(f[j]);
        l[j] = f2bf(f[j] - bf2f(h[j]));
    }
    ((u16x4*)hi)[i] = h;
    if (lo) ((u16x4*)lo)[i] = l;
}

// ---------------- QKV GEMM (pre-split bf16, LDS double-buffer prefetch) + fused RoPE ----------------
// z=0 -> Q2 bf16 hi/lo [h][s][128] (RoPE, pre-scaled 1/8); z=1 -> K2; z=2 -> V^T (single-term).
__global__ __launch_bounds__(256) void gemm_qkv_kernel(
        const u16* __restrict__ xh, const u16* __restrict__ xl,
        const u16* __restrict__ wh3, const u16* __restrict__ wl3,
        const int* __restrict__ tp,
        const float* __restrict__ cost, const float* __restrict__ sint,
        u16* __restrict__ q2, u16* __restrict__ k2, u16* __restrict__ vtb) {
    __shared__ u16 sAH[2][128 * 32], sAL[2][128 * 32], sBH[2][128 * 32], sBL[2][128 * 32];
    const int z = blockIdx.z;
    const bool full = (z != 2);            // Q,K: bf16x3 split; V: hi*hi only (linear error path)
    const u16* BH = wh3 + (size_t)z * 1048576;
    const u16* BL = wl3 + (size_t)z * 1048576;
    const int m0 = blockIdx.y * 128, n0 = blockIdx.x * 128;

    const int tid = threadIdx.x;
    const int lane = tid & 63, wid = tid >> 6;
    const int wr = wid >> 1, wc = wid & 1;
    const int l15 = lane & 15, lhi = lane >> 4;

    f32x4 acc[4][4];
#pragma unroll
    for (int i = 0; i < 4; i++)
#pragma unroll
        for (int j = 0; j < 4; j++) acc[i][j] = (f32x4){0.f, 0.f, 0.f, 0.f};

    auto stageT = [&](int kt, int b) {
#pragma unroll
        for (int i = 0; i < 2; i++) {
            const int rbase = wid * 32 + i * 16;
            const int row = rbase + (lane >> 2);
            const size_t aoff = (size_t)(m0 + row) * 1024 + kt + (lane & 3) * 8;
            const size_t boff = (size_t)(n0 + row) * 1024 + kt + (lane & 3) * 8;
            gload16(xh + aoff, sAH[b] + rbase * 32);
            gload16(BH + boff, sBH[b] + rbase * 32);
            if (full) {
                gload16(xl + aoff, sAL[b] + rbase * 32);
                gload16(BL + boff, sBL[b] + rbase * 32);
            }
        }
    };

    stageT(0, 0);
    __syncthreads();

    int buf = 0;
    for (int kt = 0; kt < 1024; kt += 32, buf ^= 1) {
        if (kt + 32 < 1024) stageT(kt + 32, buf ^ 1);   // prefetch next K-tile
        bf16x8 ah[4], al[4], bh[4], bl[4];
#pragma unroll
        for (int m = 0; m < 4; m++) {
            int row = wr * 64 + m * 16 + l15;
            ah[m] = *(const bf16x8*)(sAH[buf] + row * 32 + 8 * lhi);
            if (full) al[m] = *(const bf16x8*)(sAL[buf] + row * 32 + 8 * lhi);
        }
#pragma unroll
        for (int n = 0; n < 4; n++) {
            int row = wc * 64 + n * 16 + l15;
            bh[n] = *(const bf16x8*)(sBH[buf] + row * 32 + 8 * lhi);
            if (full) bl[n] = *(const bf16x8*)(sBL[buf] + row * 32 + 8 * lhi);
        }
#pragma unroll
        for (int m = 0; m < 4; m++)
#pragma unroll
            for (int n = 0; n < 4; n++) {
                if (full) {
                    acc[m][n] = __builtin_amdgcn_mfma_f32_16x16x32_bf16(al[m], bh[n], acc[m][n], 0, 0, 0);
                    acc[m][n] = __builtin_amdgcn_mfma_f32_16x16x32_bf16(ah[m], bl[n], acc[m][n], 0, 0, 0);
                }
                acc[m][n] = __builtin_amdgcn_mfma_f32_16x16x32_bf16(ah[m], bh[n], acc[m][n], 0, 0, 0);
            }
        __syncthreads();   // drains vmcnt: next buffer staged; this buffer free for re-stage
    }

    if (z == 2) {
#pragma unroll
        for (int m = 0; m < 4; m++)
#pragma unroll
            for (int n = 0; n < 4; n++)
#pragma unroll
                for (int j = 0; j < 4; j++) {
                    int srow = m0 + wr * 64 + m * 16 + lhi * 4 + j;
                    int eg = n0 + wc * 64 + n * 16 + l15;
                    vtb[(size_t)eg * S_LEN + srow] = f2bf(acc[m][n][j]);
                }
        return;
    }

    u16* outp = (z == 0) ? q2 : k2;
    const float qscale = (z == 0) ? 0.125f : 1.0f;   // fold 1/sqrt(64) into Q (exact pow2)
    const int head = (n0 + wc * 64) >> 6;
#pragma unroll
    for (int m = 0; m < 4; m++)
#pragma unroll
        for (int n = 0; n < 4; n++) {
            const int dh = n * 16 + l15;
            const int pairi = dh >> 1;
            const bool even = (dh & 1) == 0;
#pragma unroll
            for (int j = 0; j < 4; j++) {
                int srow = m0 + wr * 64 + m * 16 + lhi * 4 + j;
                float v = acc[m][n][j];
                float pv = __shfl_xor(v, 1);
                int pos = tp[srow];
                float cc = cost[(size_t)pos * 32 + pairi];
                float ss = sint[(size_t)pos * 32 + pairi];
                float e = even ? v : pv;
                float o = even ? pv : v;
                float res = (even ? (e * cc - o * ss) : (e * ss + o * cc)) * qscale;
                u16 hb = f2bf(res);
                u16 lb = f2bf(res - bf2f(hb));
                size_t base = ((size_t)head * S_LEN + srow) * 128 + dh;
                outp[base] = hb;
                outp[base + 64] = lb;
            }
        }
}

// ---------------- Flash attention: half-pair blocks, 4 waves, 2 blocks/CU ----------------
// grid (32, 16): p = bx&15 -> tile pair (31-p, p); half = bx>>4 -> rows [half*64, half*64+64).
// Every block: 4 waves x 16 rows, exactly 66 kv-steps (uniform). 2 co-resident blocks/CU
// have INDEPENDENT barriers: one block's vmcnt-drain overlaps the sibling's compute.
// LDS 57.2 KB/block -> 2 blocks/CU. Defer-max softmax; setprio around MFMA clusters.
#define PLD32 36
__global__ __launch_bounds__(256) void attn_kernel(const u16* __restrict__ q2,
                                                   const u16* __restrict__ k2,
                                                   const u16* __restrict__ vtb,
                                                   u16* __restrict__ attnb) {
    const int h = blockIdx.y;
    const int p = blockIdx.x & 15;         // pair id -> tiles (31-p, p)
    const int half = blockIdx.x >> 4;      // which 64-row half of each tile
    const int wid = threadIdx.x >> 6;      // 0..3
    const int lane = threadIdx.x & 63;
    const int l15 = lane & 15, lhi = lane >> 4;

    const u16* Qh2 = q2 + (size_t)h * S_LEN * 128;
    const u16* Kh2 = k2 + (size_t)h * S_LEN * 128;
    const u16* Vh  = vtb + (size_t)h * 64 * S_LEN;

    __shared__ u16 sK[2][64 * 128];        // 2 x 16 KiB
    __shared__ u16 sV[2][64 * 64];         // 2 x 8 KiB
    __shared__ unsigned pls[4][16 * PLD32];
    unsigned* myP = pls[wid];

    const int tileA = 31 - p, tileB = p;
    const int eA = 2 * tileA + 2, eB = 2 * tileB + 2;
    const int etot = eA + eB;              // 66 for every block

    auto stage = [&](int t, int b) {
        const int k = (t < eA) ? t : (t - eA);
        const int k0 = k * 64;
        // K: 16 rows per wave (4 gload16 x 4 rows)
#pragma unroll
        for (int i = 0; i < 4; i++) {
            const int rbase = wid * 16 + i * 4;
            const int row = rbase + (lane >> 4);
            const int cb = (lane & 15) * 16;
            const int csw = cb ^ ((row & 7) << 4);
            gload16(Kh2 + (size_t)(k0 + row) * 128 + (csw >> 1), &sK[b][rbase * 128]);
        }
        // V: 16 rows per wave (2 gload16 x 8 rows)
#pragma unroll
        for (int i = 0; i < 2; i++) {
            const int rbase = wid * 16 + i * 8;
            const int row = rbase + (lane >> 3);
            const int cb = (lane & 7) * 16;
            const int csw = cb ^ ((row & 7) << 4);
            gload16(Vh + (size_t)row * S_LEN + k0 + (csw >> 1), &sV[b][rbase * 64]);
        }
    };

    bf16x8 qhf[2], qlf[2];
    f32x4 oT[4];
    float m_run, l_run;                    // m_run row-uniform; l_run PER-LANE partial
    int q0 = 0, my_nkb = 0;

    auto initPass = [&](int tile) {
        q0 = tile * 128 + half * 64 + wid * 16;
        my_nkb = ((q0 + 15) >> 6) + 1;
#pragma unroll
        for (int ks = 0; ks < 2; ks++) {
            const u16* qp = Qh2 + (size_t)(q0 + l15) * 128 + ks * 32 + 8 * lhi;
            qhf[ks] = *(const bf16x8*)(qp);
            qlf[ks] = *(const bf16x8*)(qp + 64);
        }
        m_run = -1e30f;
        l_run = 0.f;
#pragma unroll
        for (int m = 0; m < 4; m++) oT[m] = (f32x4){0.f, 0.f, 0.f, 0.f};
    };

    auto writeOut = [&]() {
        float lt = l_run;
        lt += __shfl_xor(lt, 16);
        lt += __shfl_xor(lt, 32);
        const float inv = 1.0f / lt;
        const int srow = q0 + l15;
#pragma unroll
        for (int m = 0; m < 4; m++)
#pragma unroll
            for (int j = 0; j < 4; j++)
                attnb[(size_t)srow * 1024 + h * 64 + m * 16 + lhi * 4 + j] =
                    f2bf(oT[m][j] * inv);
    };

    auto doStep = [&](int t, int b) {
        const int k = (t < eA) ? t : (t - eA);
        if (k >= my_nkb) return;
        const int k0 = k * 64;
        bf16x8 kh[4][2], kl[4][2], vfr[4][2];
#pragma unroll
        for (int m = 0; m < 4; m++) {
            const int r = m * 16 + l15;
            const int sw = (r & 7) << 4;
            const u16* kp = &sK[b][r * 128];
            const u16* vp = &sV[b][r * 64];
#pragma unroll
            for (int c = 0; c < 2; c++) {
                kh[m][c] = *(const bf16x8*)(kp + (((c * 64 + lhi * 16) ^ sw) >> 1));
                kl[m][c] = *(const bf16x8*)(kp + (((128 + c * 64 + lhi * 16) ^ sw) >> 1));
                vfr[m][c] = *(const bf16x8*)(vp + (((c * 64 + lhi * 16) ^ sw) >> 1));
            }
        }
        f32x4 sT[4];
        __builtin_amdgcn_s_setprio(1);
#pragma unroll
        for (int m = 0; m < 4; m++) {
            f32x4 a = (f32x4){0.f, 0.f, 0.f, 0.f};
            a = __builtin_amdgcn_mfma_f32_16x16x32_bf16(kh[m][0], qlf[0], a, 0, 0, 0);
            a = __builtin_amdgcn_mfma_f32_16x16x32_bf16(kh[m][1], qlf[1], a, 0, 0, 0);
            a = __builtin_amdgcn_mfma_f32_16x16x32_bf16(kl[m][0], qhf[0], a, 0, 0, 0);
            a = __builtin_amdgcn_mfma_f32_16x16x32_bf16(kl[m][1], qhf[1], a, 0, 0, 0);
            a = __builtin_amdgcn_mfma_f32_16x16x32_bf16(kh[m][0], qhf[0], a, 0, 0, 0);
            a = __builtin_amdgcn_mfma_f32_16x16x32_bf16(kh[m][1], qhf[1], a, 0, 0, 0);
            sT[m] = a;
        }
        __builtin_amdgcn_s_setprio(0);
        const bool last = (k == my_nkb - 1);
        const int qg = q0 + l15;
        if (last) {
#pragma unroll
            for (int m = 0; m < 4; m++)
#pragma unroll
                for (int j = 0; j < 4; j++) {
                    int kg = k0 + m * 16 + lhi * 4 + j;
                    if (kg > qg) sT[m][j] = -1e30f;
                }
        }
        float t0 = fmaxf(fmaxf(sT[0][0], sT[0][1]), fmaxf(sT[0][2], sT[0][3]));
        float t1 = fmaxf(fmaxf(sT[1][0], sT[1][1]), fmaxf(sT[1][2], sT[1][3]));
        float t2 = fmaxf(fmaxf(sT[2][0], sT[2][1]), fmaxf(sT[2][2], sT[2][3]));
        float t3 = fmaxf(fmaxf(sT[3][0], sT[3][1]), fmaxf(sT[3][2], sT[3][3]));
        float lane_max = fmaxf(fmaxf(t0, t1), fmaxf(t2, t3));
        if (__any(lane_max > m_run + 8.0f)) {     // slow path: real row-max + rescale
            float mx = fmaxf(m_run, lane_max);
            mx = fmaxf(mx, __shfl_xor(mx, 16));
            mx = fmaxf(mx, __shfl_xor(mx, 32));
            float alpha = __expf(m_run - mx);      // row-uniform (0 on first tile)
            l_run *= alpha;
#pragma unroll
            for (int m = 0; m < 4; m++) {
                oT[m][0] *= alpha; oT[m][1] *= alpha;
                oT[m][2] *= alpha; oT[m][3] *= alpha;
            }
            m_run = mx;
        }
        const float mr = m_run;
        float s0 = 0.f, s1 = 0.f, s2 = 0.f, s3 = 0.f;
#pragma unroll
        for (int m = 0; m < 4; m++) {
            float p0 = __expf(sT[m][0] - mr);
            float p1 = __expf(sT[m][1] - mr);
            float p2 = __expf(sT[m][2] - mr);
            float p3 = __expf(sT[m][3] - mr);
            sT[m][0] = p0; sT[m][1] = p1; sT[m][2] = p2; sT[m][3] = p3;
            s0 += p0; s1 += p1; s2 += p2; s3 += p3;
        }
        l_run += (s0 + s1) + (s2 + s3);            // per-lane partial
#pragma unroll
        for (int m = 0; m < 4; m++) {
            uint2v pk;
            pk[0] = pack2bf(sT[m][0], sT[m][1]);
            pk[1] = pack2bf(sT[m][2], sT[m][3]);
            *(uint2v*)(myP + l15 * PLD32 + m * 8 + lhi * 2) = pk;
        }
        bf16x8 pf[2];
#pragma unroll
        for (int ks = 0; ks < 2; ks++) {
            uint4v pw = *(const uint4v*)(myP + l15 * PLD32 + ks * 16 + 4 * lhi);
            pf[ks] = __builtin_bit_cast(bf16x8, pw);
        }
        __builtin_amdgcn_s_setprio(1);
#pragma unroll
        for (int m = 0; m < 4; m++) {
            oT[m] = __builtin_amdgcn_mfma_f32_16x16x32_bf16(vfr[m][0], pf[0], oT[m], 0, 0, 0);
            oT[m] = __builtin_amdgcn_mfma_f32_16x16x32_bf16(vfr[m][1], pf[1], oT[m], 0, 0, 0);
        }
        __builtin_amdgcn_s_setprio(0);
    };

    stage(0, 0);
    initPass(tileA);
    __syncthreads();   // drains vmcnt: buf0 ready

    int cur = 0;
    for (int t = 0; t < etot; ++t) {
        if (t + 1 < etot) stage(t + 1, cur ^ 1);
        if (t == eA) { writeOut(); initPass(tileB); }
        doStep(t, cur);
        __syncthreads();   // drains vmcnt; sibling block's waves cover this stall
        cur ^= 1;
    }
    writeOut();
}

// ---------------- output projection: bf16 x bf16 -> fp32, dbuf gload16-staged ----------------
__global__ __launch_bounds__(256) void gemm_out_kernel(const u16* __restrict__ attnb,
                                                       const u16* __restrict__ woh,
                                                       float* __restrict__ out) {
    __shared__ u16 sA[2][128 * 32];
    __shared__ u16 sB[2][128 * 32];
    const int m0 = blockIdx.y * 128, n0 = blockIdx.x * 128;
    const int tid = threadIdx.x;
    const int lane = tid & 63, wid = tid >> 6;
    const int wr = wid >> 1, wc = wid & 1;
    const int l15 = lane & 15, lhi = lane >> 4;

    f32x4 acc[4][4];
#pragma unroll
    for (int i = 0; i < 4; i++)
#pragma unroll
        for (int j = 0; j < 4; j++) acc[i][j] = (f32x4){0.f, 0.f, 0.f, 0.f};

    auto stageT = [&](int kt, int b) {
#pragma unroll
        for (int i = 0; i < 2; i++) {
            const int rbase = wid * 32 + i * 16;
            const int row = rbase + (lane >> 2);
            gload16(attnb + (size_t)(m0 + row) * 1024 + kt + (lane & 3) * 8, sA[b] + rbase * 32);
            gload16(woh + (size_t)(n0 + row) * 1024 + kt + (lane & 3) * 8, sB[b] + rbase * 32);
        }
    };

    stageT(0, 0);
    __syncthreads();

    int buf = 0;
    for (int kt = 0; kt < 1024; kt += 32, buf ^= 1) {
        if (kt + 32 < 1024) stageT(kt + 32, buf ^ 1);
        bf16x8 af[4], bfr[4];
#pragma unroll
        for (int m = 0; m < 4; m++) {
            int row = wr * 64 + m * 16 + l15;
            af[m] = *(const bf16x8*)(sA[buf] + row * 32 + 8 * lhi);
        }
#pragma unroll
        for (int n = 0; n < 4; n++) {
            int row = wc * 64 + n * 16 + l15;
            bfr[n] = *(const bf16x8*)(sB[buf] + row * 32 + 8 * lhi);
        }
#pragma unroll
        for (int m = 0; m < 4; m++)
#pragma unroll
            for (int n = 0; n < 4; n++)
                acc[m][n] = __builtin_amdgcn_mfma_f32_16x16x32_bf16(af[m], bfr[n], acc[m][n], 0, 0, 0);
        __syncthreads();
    }

#pragma unroll
    for (int m = 0; m < 4; m++)
#pragma unroll
        for (int n = 0; n < 4; n++)
#pragma unroll
            for (int j = 0; j < 4; j++) {
                int srow = m0 + wr * 64 + m * 16 + lhi * 4 + j;
                int eg = n0 + wc * 64 + n * 16 + l15;
                out[(size_t)srow * 1024 + eg] = acc[m][n][j];
            }
}

// ---------------- host launch ----------------
extern "C" void kernel_launch(void* const* d_in, const int* in_sizes, int n_in,
                              void* d_out, int out_size, void* d_ws, size_t ws_size,
                              hipStream_t stream) {
    const float* x = (const float*)d_in[0];
    const int* tp = (const int*)d_in[1];
    const float* wq = (const float*)d_in[2];
    const float* wk = (const float*)d_in[3];
    const float* wv = (const float*)d_in[4];
    const float* wo = (const float*)d_in[5];
    float* out = (float*)d_out;
    char* ws = (char*)d_ws;

    u16* Q2    = (u16*)(ws + 0);           // 16 MiB bf16 [16][4096][128] hi/lo, Q pre-scaled 1/8
    u16* K2    = (u16*)(ws + 16777216);    // 16 MiB
    u16* VTB   = (u16*)(ws + 33554432);    // 8 MiB bf16 [h*64+dh][4096]
    u16* ATTNB = (u16*)(ws + 41943040);    // 8 MiB bf16 [4096][1024]
    float* COST = (float*)(ws + 50331648); // 512 KiB
    float* SINT = (float*)(ws + 50855936); // 512 KiB
    u16* XH  = (u16*)(ws + 51380224);      // 8 MiB bf16 [4096][1024]
    u16* XL  = (u16*)(ws + 59768832);      // 8 MiB
    u16* WH3 = (u16*)(ws + 68157440);      // 6 MiB bf16 [3][1024][1024]
    u16* WL3 = (u16*)(ws + 74448896);      // 6 MiB
    u16* WOH = (u16*)(ws + 80740352);      // 2 MiB bf16 [1024][1024]

    rope_table_kernel<<<512, 256, 0, stream>>>(COST, SINT);

    split_kernel<<<4096, 256, 0, stream>>>(x, XH, XL, 1048576);
    split_kernel<<<1024, 256, 0, stream>>>(wq, WH3,            WL3,            262144);
    split_kernel<<<1024, 256, 0, stream>>>(wk, WH3 + 1048576,  WL3 + 1048576,  262144);
    split_kernel<<<1024, 256, 0, stream>>>(wv, WH3 + 2097152,  WL3 + 2097152,  262144);
    split_kernel<<<1024, 256, 0, stream>>>(wo, WOH,            (u16*)nullptr,  262144);

    gemm_qkv_kernel<<<dim3(8, 32, 3), 256, 0, stream>>>(
        XH, XL, WH3, WL3, tp, COST, SINT, Q2, K2, VTB);

    attn_kernel<<<dim3(32, 16), 256, 0, stream>>>(Q2, K2, VTB, ATTNB);

    gemm_out_kernel<<<dim3(8, 32), 256, 0, stream>>>(ATTNB, WOH, out);
}

// Round 20
// 229.540 us; speedup vs baseline: 1.0975x; 1.0975x over previous
//
#include <hip/hip_runtime.h>
#include <hip/hip_bf16.h>
#include <math.h>

#define S_LEN 4096
#define DMODEL 1024
#define NHEADS 16
#define DHEAD 64

typedef unsigned short u16;
typedef short bf16x8 __attribute__((ext_vector_type(8)));
typedef float f32x4 __attribute__((ext_vector_type(4)));
typedef u16 u16x4 __attribute__((ext_vector_type(4)));
typedef u16 u16x8 __attribute__((ext_vector_type(8)));
typedef unsigned uint4v __attribute__((ext_vector_type(4)));
typedef unsigned uint2v __attribute__((ext_vector_type(2)));

__device__ __forceinline__ u16 f2bf(float f) {
    unsigned u = __builtin_bit_cast(unsigned, f);
    u = (u + 0x7FFFu + ((u >> 16) & 1u)) >> 16;
    return (u16)u;
}
__device__ __forceinline__ float bf2f(u16 b) {
    return __builtin_bit_cast(float, ((unsigned)b) << 16);
}
// packed f32x2 -> u32 of 2 bf16 (RNE) via HIP intrinsic type; memcpy = free bitcast in IR
__device__ __forceinline__ unsigned pack2bf(float lo, float hi) {
    __hip_bfloat162 c = __float22bfloat162_rn(make_float2(lo, hi));
    unsigned u;
    __builtin_memcpy(&u, &c, 4);
    return u;
}

// async global->LDS, 16B per lane; LDS dest = wave-uniform base + lane*16
__device__ __forceinline__ void gload16(const void* g, void* l) {
    __builtin_amdgcn_global_load_lds((const __attribute__((address_space(1))) void*)g,
                                     (__attribute__((address_space(3))) void*)l, 16, 0, 0);
}

// ---------------- RoPE tables (fp32-faithful to numpy float32 path) ----------------
__global__ void rope_table_kernel(float* __restrict__ cost, float* __restrict__ sint) {
    int tid = blockIdx.x * blockDim.x + threadIdx.x;  // 4096*32
    int i = tid & 31;
    int pos = tid >> 5;
    double e = (double)(2 * i) / 64.0;
    float t32 = (float)pow(10000.0, e);
    float freq = 1.0f / t32;
    float ang = (float)pos * freq;
    cost[tid] = (float)cos((double)ang);
    sint[tid] = (float)sin((double)ang);
}

// ---------------- fp32 -> bf16 hi (+ optional lo residual) ----------------
__global__ void split_kernel(const float* __restrict__ in, u16* __restrict__ hi,
                             u16* __restrict__ lo, int n4) {
    int i = blockIdx.x * blockDim.x + threadIdx.x;
    if (i >= n4) return;
    float4 v = ((const float4*)in)[i];
    float f[4] = {v.x, v.y, v.z, v.w};
    u16x4 h, l;
#pragma unroll
    for (int j = 0; j < 4; j++) {
        h[j] = f2bf(f[j]);
        l[j] = f2bf(f[j] - bf2f(h[j]));
    }
    ((u16x4*)hi)[i] = h;
    if (lo) ((u16x4*)lo)[i] = l;
}

// ---------------- QKV GEMM (pre-split bf16, LDS double-buffer prefetch) + fused RoPE ----------------
// z=0 -> Q2 bf16 hi/lo [h][s][128] (RoPE, pre-scaled 1/8); z=1 -> K2; z=2 -> V^T (single-term).
__global__ __launch_bounds__(256) void gemm_qkv_kernel(
        const u16* __restrict__ xh, const u16* __restrict__ xl,
        const u16* __restrict__ wh3, const u16* __restrict__ wl3,
        const int* __restrict__ tp,
        const float* __restrict__ cost, const float* __restrict__ sint,
        u16* __restrict__ q2, u16* __restrict__ k2, u16* __restrict__ vtb) {
    __shared__ u16 sAH[2][128 * 32], sAL[2][128 * 32], sBH[2][128 * 32], sBL[2][128 * 32];
    const int z = blockIdx.z;
    const bool full = (z != 2);            // Q,K: bf16x3 split; V: hi*hi only (linear error path)
    const u16* BH = wh3 + (size_t)z * 1048576;
    const u16* BL = wl3 + (size_t)z * 1048576;
    const int m0 = blockIdx.y * 128, n0 = blockIdx.x * 128;

    const int tid = threadIdx.x;
    const int lane = tid & 63, wid = tid >> 6;
    const int wr = wid >> 1, wc = wid & 1;
    const int l15 = lane & 15, lhi = lane >> 4;

    f32x4 acc[4][4];
#pragma unroll
    for (int i = 0; i < 4; i++)
#pragma unroll
        for (int j = 0; j < 4; j++) acc[i][j] = (f32x4){0.f, 0.f, 0.f, 0.f};

    auto stageT = [&](int kt, int b) {
#pragma unroll
        for (int i = 0; i < 2; i++) {
            const int rbase = wid * 32 + i * 16;
            const int row = rbase + (lane >> 2);
            const size_t aoff = (size_t)(m0 + row) * 1024 + kt + (lane & 3) * 8;
            const size_t boff = (size_t)(n0 + row) * 1024 + kt + (lane & 3) * 8;
            gload16(xh + aoff, sAH[b] + rbase * 32);
            gload16(BH + boff, sBH[b] + rbase * 32);
            if (full) {
                gload16(xl + aoff, sAL[b] + rbase * 32);
                gload16(BL + boff, sBL[b] + rbase * 32);
            }
        }
    };

    stageT(0, 0);
    __syncthreads();

    int buf = 0;
    for (int kt = 0; kt < 1024; kt += 32, buf ^= 1) {
        if (kt + 32 < 1024) stageT(kt + 32, buf ^ 1);   // prefetch next K-tile
        bf16x8 ah[4], al[4], bh[4], bl[4];
#pragma unroll
        for (int m = 0; m < 4; m++) {
            int row = wr * 64 + m * 16 + l15;
            ah[m] = *(const bf16x8*)(sAH[buf] + row * 32 + 8 * lhi);
            if (full) al[m] = *(const bf16x8*)(sAL[buf] + row * 32 + 8 * lhi);
        }
#pragma unroll
        for (int n = 0; n < 4; n++) {
            int row = wc * 64 + n * 16 + l15;
            bh[n] = *(const bf16x8*)(sBH[buf] + row * 32 + 8 * lhi);
            if (full) bl[n] = *(const bf16x8*)(sBL[buf] + row * 32 + 8 * lhi);
        }
#pragma unroll
        for (int m = 0; m < 4; m++)
#pragma unroll
            for (int n = 0; n < 4; n++) {
                if (full) {
                    acc[m][n] = __builtin_amdgcn_mfma_f32_16x16x32_bf16(al[m], bh[n], acc[m][n], 0, 0, 0);
                    acc[m][n] = __builtin_amdgcn_mfma_f32_16x16x32_bf16(ah[m], bl[n], acc[m][n], 0, 0, 0);
                }
                acc[m][n] = __builtin_amdgcn_mfma_f32_16x16x32_bf16(ah[m], bh[n], acc[m][n], 0, 0, 0);
            }
        __syncthreads();   // drains vmcnt: next buffer staged; this buffer free for re-stage
    }

    if (z == 2) {
#pragma unroll
        for (int m = 0; m < 4; m++)
#pragma unroll
            for (int n = 0; n < 4; n++)
#pragma unroll
                for (int j = 0; j < 4; j++) {
                    int srow = m0 + wr * 64 + m * 16 + lhi * 4 + j;
                    int eg = n0 + wc * 64 + n * 16 + l15;
                    vtb[(size_t)eg * S_LEN + srow] = f2bf(acc[m][n][j]);
                }
        return;
    }

    u16* outp = (z == 0) ? q2 : k2;
    const float qscale = (z == 0) ? 0.125f : 1.0f;   // fold 1/sqrt(64) into Q (exact pow2)
    const int head = (n0 + wc * 64) >> 6;
#pragma unroll
    for (int m = 0; m < 4; m++)
#pragma unroll
        for (int n = 0; n < 4; n++) {
            const int dh = n * 16 + l15;
            const int pairi = dh >> 1;
            const bool even = (dh & 1) == 0;
#pragma unroll
            for (int j = 0; j < 4; j++) {
                int srow = m0 + wr * 64 + m * 16 + lhi * 4 + j;
                float v = acc[m][n][j];
                float pv = __shfl_xor(v, 1);
                int pos = tp[srow];
                float cc = cost[(size_t)pos * 32 + pairi];
                float ss = sint[(size_t)pos * 32 + pairi];
                float e = even ? v : pv;
                float o = even ? pv : v;
                float res = (even ? (e * cc - o * ss) : (e * ss + o * cc)) * qscale;
                u16 hb = f2bf(res);
                u16 lb = f2bf(res - bf2f(hb));
                size_t base = ((size_t)head * S_LEN + srow) * 128 + dh;
                outp[base] = hb;
                outp[base + 64] = lb;
            }
        }
}

// ---------------- Flash attention: 8 waves x 16 q-rows, shared K/V, 4-buffer, 2-step ----------------
// r16/r18 structure — measured optimum of this design space (117 us). Paired q-tiles
// (uniform 66 steps), shared staging across 8 waves (2 waves/SIMD TLP), 4-buffer K/V with
// one barrier per two steps, defer-max softmax (THR=8, per-lane l partial), setprio(1)
// around MFMA clusters (neutral-measured, kept).
#define PLD32 36
__global__ __launch_bounds__(512) void attn_kernel(const u16* __restrict__ q2,
                                                   const u16* __restrict__ k2,
                                                   const u16* __restrict__ vtb,
                                                   u16* __restrict__ attnb) {
    const int h = blockIdx.y;
    const int p = blockIdx.x;              // pair id 0..15 -> tiles (31-p, p)
    const int wid = threadIdx.x >> 6;      // 0..7
    const int lane = threadIdx.x & 63;
    const int l15 = lane & 15, lhi = lane >> 4;

    const u16* Qh2 = q2 + (size_t)h * S_LEN * 128;
    const u16* Kh2 = k2 + (size_t)h * S_LEN * 128;
    const u16* Vh  = vtb + (size_t)h * 64 * S_LEN;

    __shared__ u16 sK[4][64 * 128];        // 4 x 16 KiB
    __shared__ u16 sV[4][64 * 64];         // 4 x 8 KiB
    __shared__ unsigned pls[8][16 * PLD32];
    unsigned* myP = pls[wid];

    const int tileA = 31 - p, tileB = p;
    const int eA = 2 * tileA + 2, eB = 2 * tileB + 2;
    const int etot = eA + eB;              // 66 for every block (eA, eB, etot all even)

    auto stage = [&](int t, int b) {
        const int k = (t < eA) ? t : (t - eA);
        const int k0 = k * 64;
        // K: 8 rows per wave (2 gload16 x 4 rows)
#pragma unroll
        for (int i = 0; i < 2; i++) {
            const int rbase = wid * 8 + i * 4;
            const int row = rbase + (lane >> 4);
            const int cb = (lane & 15) * 16;
            const int csw = cb ^ ((row & 7) << 4);
            gload16(Kh2 + (size_t)(k0 + row) * 128 + (csw >> 1), &sK[b][rbase * 128]);
        }
        // V: 8 rows per wave (1 gload16 x 8 rows)
        {
            const int rbase = wid * 8;
            const int row = rbase + (lane >> 3);
            const int cb = (lane & 7) * 16;
            const int csw = cb ^ ((row & 7) << 4);
            gload16(Vh + (size_t)row * S_LEN + k0 + (csw >> 1), &sV[b][rbase * 64]);
        }
    };

    bf16x8 qhf[2], qlf[2];
    f32x4 oT[4];
    float m_run, l_run;                    // m_run row-uniform; l_run PER-LANE partial
    int q0 = 0, my_nkb = 0;

    auto initPass = [&](int tile) {
        q0 = tile * 128 + wid * 16;
        my_nkb = ((q0 + 15) >> 6) + 1;
#pragma unroll
        for (int ks = 0; ks < 2; ks++) {
            const u16* qp = Qh2 + (size_t)(q0 + l15) * 128 + ks * 32 + 8 * lhi;
            qhf[ks] = *(const bf16x8*)(qp);
            qlf[ks] = *(const bf16x8*)(qp + 64);
        }
        m_run = -1e30f;
        l_run = 0.f;
#pragma unroll
        for (int m = 0; m < 4; m++) oT[m] = (f32x4){0.f, 0.f, 0.f, 0.f};
    };

    auto writeOut = [&]() {
        float lt = l_run;
        lt += __shfl_xor(lt, 16);
        lt += __shfl_xor(lt, 32);
        const float inv = 1.0f / lt;
        const int srow = q0 + l15;
#pragma unroll
        for (int m = 0; m < 4; m++)
#pragma unroll
            for (int j = 0; j < 4; j++)
                attnb[(size_t)srow * 1024 + h * 64 + m * 16 + lhi * 4 + j] =
                    f2bf(oT[m][j] * inv);
    };

    auto doStep = [&](int t, int b) {
        const int k = (t < eA) ? t : (t - eA);
        if (k >= my_nkb) return;
        const int k0 = k * 64;
        bf16x8 kh[4][2], kl[4][2], vfr[4][2];
#pragma unroll
        for (int m = 0; m < 4; m++) {
            const int r = m * 16 + l15;
            const int sw = (r & 7) << 4;
            const u16* kp = &sK[b][r * 128];
            const u16* vp = &sV[b][r * 64];
#pragma unroll
            for (int c = 0; c < 2; c++) {
                kh[m][c] = *(const bf16x8*)(kp + (((c * 64 + lhi * 16) ^ sw) >> 1));
                kl[m][c] = *(const bf16x8*)(kp + (((128 + c * 64 + lhi * 16) ^ sw) >> 1));
                vfr[m][c] = *(const bf16x8*)(vp + (((c * 64 + lhi * 16) ^ sw) >> 1));
            }
        }
        f32x4 sT[4];
        __builtin_amdgcn_s_setprio(1);
#pragma unroll
        for (int m = 0; m < 4; m++) {
            f32x4 a = (f32x4){0.f, 0.f, 0.f, 0.f};
            a = __builtin_amdgcn_mfma_f32_16x16x32_bf16(kh[m][0], qlf[0], a, 0, 0, 0);
            a = __builtin_amdgcn_mfma_f32_16x16x32_bf16(kh[m][1], qlf[1], a, 0, 0, 0);
            a = __builtin_amdgcn_mfma_f32_16x16x32_bf16(kl[m][0], qhf[0], a, 0, 0, 0);
            a = __builtin_amdgcn_mfma_f32_16x16x32_bf16(kl[m][1], qhf[1], a, 0, 0, 0);
            a = __builtin_amdgcn_mfma_f32_16x16x32_bf16(kh[m][0], qhf[0], a, 0, 0, 0);
            a = __builtin_amdgcn_mfma_f32_16x16x32_bf16(kh[m][1], qhf[1], a, 0, 0, 0);
            sT[m] = a;
        }
        __builtin_amdgcn_s_setprio(0);
        const bool last = (k == my_nkb - 1);
        const int qg = q0 + l15;
        if (last) {
#pragma unroll
            for (int m = 0; m < 4; m++)
#pragma unroll
                for (int j = 0; j < 4; j++) {
                    int kg = k0 + m * 16 + lhi * 4 + j;
                    if (kg > qg) sT[m][j] = -1e30f;
                }
        }
        float t0 = fmaxf(fmaxf(sT[0][0], sT[0][1]), fmaxf(sT[0][2], sT[0][3]));
        float t1 = fmaxf(fmaxf(sT[1][0], sT[1][1]), fmaxf(sT[1][2], sT[1][3]));
        float t2 = fmaxf(fmaxf(sT[2][0], sT[2][1]), fmaxf(sT[2][2], sT[2][3]));
        float t3 = fmaxf(fmaxf(sT[3][0], sT[3][1]), fmaxf(sT[3][2], sT[3][3]));
        float lane_max = fmaxf(fmaxf(t0, t1), fmaxf(t2, t3));
        if (__any(lane_max > m_run + 8.0f)) {     // slow path: real row-max + rescale
            float mx = fmaxf(m_run, lane_max);
            mx = fmaxf(mx, __shfl_xor(mx, 16));
            mx = fmaxf(mx, __shfl_xor(mx, 32));
            float alpha = __expf(m_run - mx);      // row-uniform (0 on first tile)
            l_run *= alpha;
#pragma unroll
            for (int m = 0; m < 4; m++) {
                oT[m][0] *= alpha; oT[m][1] *= alpha;
                oT[m][2] *= alpha; oT[m][3] *= alpha;
            }
            m_run = mx;
        }
        const float mr = m_run;
        float s0 = 0.f, s1 = 0.f, s2 = 0.f, s3 = 0.f;
#pragma unroll
        for (int m = 0; m < 4; m++) {
            float p0 = __expf(sT[m][0] - mr);
            float p1 = __expf(sT[m][1] - mr);
            float p2 = __expf(sT[m][2] - mr);
            float p3 = __expf(sT[m][3] - mr);
            sT[m][0] = p0; sT[m][1] = p1; sT[m][2] = p2; sT[m][3] = p3;
            s0 += p0; s1 += p1; s2 += p2; s3 += p3;
        }
        l_run += (s0 + s1) + (s2 + s3);            // per-lane partial
#pragma unroll
        for (int m = 0; m < 4; m++) {
            uint2v pk;
            pk[0] = pack2bf(sT[m][0], sT[m][1]);
            pk[1] = pack2bf(sT[m][2], sT[m][3]);
            *(uint2v*)(myP + l15 * PLD32 + m * 8 + lhi * 2) = pk;
        }
        bf16x8 pf[2];
#pragma unroll
        for (int ks = 0; ks < 2; ks++) {
            uint4v pw = *(const uint4v*)(myP + l15 * PLD32 + ks * 16 + 4 * lhi);
            pf[ks] = __builtin_bit_cast(bf16x8, pw);
        }
        __builtin_amdgcn_s_setprio(1);
#pragma unroll
        for (int m = 0; m < 4; m++) {
            oT[m] = __builtin_amdgcn_mfma_f32_16x16x32_bf16(vfr[m][0], pf[0], oT[m], 0, 0, 0);
            oT[m] = __builtin_amdgcn_mfma_f32_16x16x32_bf16(vfr[m][1], pf[1], oT[m], 0, 0, 0);
        }
        __builtin_amdgcn_s_setprio(0);
    };

    stage(0, 0);
    stage(1, 1);
    initPass(tileA);
    __syncthreads();   // drains vmcnt: buf0, buf1 ready

    for (int t = 0; t < etot; t += 2) {
        if (t + 2 < etot) stage(t + 2, (t + 2) & 3);
        if (t + 3 < etot) stage(t + 3, (t + 3) & 3);
        if (t == eA) { writeOut(); initPass(tileB); }   // eA even -> only at iteration top
        doStep(t, t & 3);
        doStep(t + 1, (t + 1) & 3);
        __syncthreads();   // drains vmcnt: buffers (t+2)&3, (t+3)&3 staged; t&3,(t+1)&3 free
    }
    writeOut();
}

// ---------------- output projection: bf16 x bf16 -> fp32, dbuf gload16-staged ----------------
__global__ __launch_bounds__(256) void gemm_out_kernel(const u16* __restrict__ attnb,
                                                       const u16* __restrict__ woh,
                                                       float* __restrict__ out) {
    __shared__ u16 sA[2][128 * 32];
    __shared__ u16 sB[2][128 * 32];
    const int m0 = blockIdx.y * 128, n0 = blockIdx.x * 128;
    const int tid = threadIdx.x;
    const int lane = tid & 63, wid = tid >> 6;
    const int wr = wid >> 1, wc = wid & 1;
    const int l15 = lane & 15, lhi = lane >> 4;

    f32x4 acc[4][4];
#pragma unroll
    for (int i = 0; i < 4; i++)
#pragma unroll
        for (int j = 0; j < 4; j++) acc[i][j] = (f32x4){0.f, 0.f, 0.f, 0.f};

    auto stageT = [&](int kt, int b) {
#pragma unroll
        for (int i = 0; i < 2; i++) {
            const int rbase = wid * 32 + i * 16;
            const int row = rbase + (lane >> 2);
            gload16(attnb + (size_t)(m0 + row) * 1024 + kt + (lane & 3) * 8, sA[b] + rbase * 32);
            gload16(woh + (size_t)(n0 + row) * 1024 + kt + (lane & 3) * 8, sB[b] + rbase * 32);
        }
    };

    stageT(0, 0);
    __syncthreads();

    int buf = 0;
    for (int kt = 0; kt < 1024; kt += 32, buf ^= 1) {
        if (kt + 32 < 1024) stageT(kt + 32, buf ^ 1);
        bf16x8 af[4], bfr[4];
#pragma unroll
        for (int m = 0; m < 4; m++) {
            int row = wr * 64 + m * 16 + l15;
            af[m] = *(const bf16x8*)(sA[buf] + row * 32 + 8 * lhi);
        }
#pragma unroll
        for (int n = 0; n < 4; n++) {
            int row = wc * 64 + n * 16 + l15;
            bfr[n] = *(const bf16x8*)(sB[buf] + row * 32 + 8 * lhi);
        }
#pragma unroll
        for (int m = 0; m < 4; m++)
#pragma unroll
            for (int n = 0; n < 4; n++)
                acc[m][n] = __builtin_amdgcn_mfma_f32_16x16x32_bf16(af[m], bfr[n], acc[m][n], 0, 0, 0);
        __syncthreads();
    }

#pragma unroll
    for (int m = 0; m < 4; m++)
#pragma unroll
        for (int n = 0; n < 4; n++)
#pragma unroll
            for (int j = 0; j < 4; j++) {
                int srow = m0 + wr * 64 + m * 16 + lhi * 4 + j;
                int eg = n0 + wc * 64 + n * 16 + l15;
                out[(size_t)srow * 1024 + eg] = acc[m][n][j];
            }
}

// ---------------- host launch ----------------
extern "C" void kernel_launch(void* const* d_in, const int* in_sizes, int n_in,
                              void* d_out, int out_size, void* d_ws, size_t ws_size,
                              hipStream_t stream) {
    const float* x = (const float*)d_in[0];
    const int* tp = (const int*)d_in[1];
    const float* wq = (const float*)d_in[2];
    const float* wk = (const float*)d_in[3];
    const float* wv = (const float*)d_in[4];
    const float* wo = (const float*)d_in[5];
    float* out = (float*)d_out;
    char* ws = (char*)d_ws;

    u16* Q2    = (u16*)(ws + 0);           // 16 MiB bf16 [16][4096][128] hi/lo, Q pre-scaled 1/8
    u16* K2    = (u16*)(ws + 16777216);    // 16 MiB
    u16* VTB   = (u16*)(ws + 33554432);    // 8 MiB bf16 [h*64+dh][4096]
    u16* ATTNB = (u16*)(ws + 41943040);    // 8 MiB bf16 [4096][1024]
    float* COST = (float*)(ws + 50331648); // 512 KiB
    float* SINT = (float*)(ws + 50855936); // 512 KiB
    u16* XH  = (u16*)(ws + 51380224);      // 8 MiB bf16 [4096][1024]
    u16* XL  = (u16*)(ws + 59768832);      // 8 MiB
    u16* WH3 = (u16*)(ws + 68157440);      // 6 MiB bf16 [3][1024][1024]
    u16* WL3 = (u16*)(ws + 74448896);      // 6 MiB
    u16* WOH = (u16*)(ws + 80740352);      // 2 MiB bf16 [1024][1024]

    rope_table_kernel<<<512, 256, 0, stream>>>(COST, SINT);

    split_kernel<<<4096, 256, 0, stream>>>(x, XH, XL, 1048576);
    split_kernel<<<1024, 256, 0, stream>>>(wq, WH3,            WL3,            262144);
    split_kernel<<<1024, 256, 0, stream>>>(wk, WH3 + 1048576,  WL3 + 1048576,  262144);
    split_kernel<<<1024, 256, 0, stream>>>(wv, WH3 + 2097152,  WL3 + 2097152,  262144);
    split_kernel<<<1024, 256, 0, stream>>>(wo, WOH,            (u16*)nullptr,  262144);

    gemm_qkv_kernel<<<dim3(8, 32, 3), 256, 0, stream>>>(
        XH, XL, WH3, WL3, tp, COST, SINT, Q2, K2, VTB);

    attn_kernel<<<dim3(16, 16), 512, 0, stream>>>(Q2, K2, VTB, ATTNB);

    gemm_out_kernel<<<dim3(8, 32), 256, 0, stream>>>(ATTNB, WOH, out);
}